// Round 3
// baseline (161.985 us; speedup 1.0000x reference)
//
#include <hip/hip_runtime.h>

#define B_ 4
#define C_ 64
#define H_ 256
#define W_ 256
#define HW_ (H_*W_)
#define MID_ 12
#define NPB_ 128   // gap partial slots per image (= blocks per image in prep/apply grid)

__device__ __forceinline__ float wave_reduce64(float v) {
#pragma unroll
    for (int off = 32; off; off >>= 1) v += __shfl_xor(v, off, 64);
    return v;
}

__device__ __forceinline__ void fnorm9(float* t9, const float* __restrict__ sstd) {
    float mean = 0.f;
#pragma unroll
    for (int t = 0; t < 9; ++t) mean += t9[t];
    mean *= (1.f / 9.f);
    float var = 0.f;
#pragma unroll
    for (int t = 0; t < 9; ++t) { float d = t9[t] - mean; var += d * d; }
    float inv = 1.f / (sqrtf(var * (1.f / 8.f)) + 1e-10f);
#pragma unroll
    for (int t = 0; t < 9; ++t) t9[t] = (t9[t] - mean) * inv * sstd[t];
}

// ---------- prep: read x once -> s1 (normalized) + gap1 block partials ----------
// grid (W/128, H/4, B), block 256 (=64 lanes x 4 waves), 2 px/thread
__global__ __launch_bounds__(256) void prep_kernel(const float* __restrict__ x,
    const float* __restrict__ sw, const float* __restrict__ sb,
    const float* __restrict__ sstd, float* __restrict__ sarr, float* __restrict__ gp) {
    const int tid = threadIdx.x;
    const int lane = tid & 63, wv = tid >> 6;
    const int col0 = (blockIdx.x * 64 + lane) * 2;
    const int row  = blockIdx.y * 4 + wv;
    const int b = blockIdx.z;
    __shared__ float lg[4][C_];

    float st0[9], st1[9];
#pragma unroll
    for (int t = 0; t < 9; ++t) { float bb = sb[t]; st0[t] = bb; st1[t] = bb; }

    const float* xp = x + ((size_t)b * C_) * HW_ + (size_t)row * W_ + col0;
    for (int c = 0; c < C_; ++c) {
        float2 v = *(const float2*)(xp + (size_t)c * HW_);
#pragma unroll
        for (int t = 0; t < 9; ++t) {
            float wt = sw[t * C_ + c];
            st0[t] = fmaf(v.x, wt, st0[t]);
            st1[t] = fmaf(v.y, wt, st1[t]);
        }
        float gs = wave_reduce64(v.x + v.y);
        if (lane == 0) lg[wv][c] = gs;
    }
    fnorm9(st0, sstd);
    fnorm9(st1, sstd);
    {
        float* sp = sarr + ((size_t)b * 9) * HW_ + (size_t)row * W_ + col0;
#pragma unroll
        for (int t = 0; t < 9; ++t)
            *(float2*)(sp + (size_t)t * HW_) = make_float2(st0[t], st1[t]);
    }
    __syncthreads();
    if (tid < C_) {
        float s4 = lg[0][tid] + lg[1][tid] + lg[2][tid] + lg[3][tid];
        gp[((size_t)b * C_ + tid) * NPB_ + blockIdx.y * gridDim.x + blockIdx.x] = s4;
    }
}

// ---------- cfk: reduce gap partials + SE MLP + FilterNorm -> cf (B,C,9) ----------
__global__ __launch_bounds__(256) void cfk(const float* __restrict__ gp,
    const float* __restrict__ cw1, const float* __restrict__ cb1,
    const float* __restrict__ cw2, const float* __restrict__ cb2,
    const float* __restrict__ cstd, float* __restrict__ cf) {
    const int tid = threadIdx.x;
    const int b = tid >> 6, c = tid & 63;
    __shared__ float gsm[B_][C_];
    __shared__ float hsm[B_][MID_];
    {
        const float4* p4 = (const float4*)(gp + ((size_t)b * C_ + c) * NPB_);
        float s = 0.f;
#pragma unroll
        for (int i = 0; i < NPB_ / 4; ++i) { float4 v = p4[i]; s += (v.x + v.y) + (v.z + v.w); }
        gsm[b][c] = s * (1.f / HW_);
    }
    __syncthreads();
    if (tid < B_ * MID_) {
        int b2 = tid / MID_, m = tid % MID_;
        float a = cb1[m];
        for (int cc = 0; cc < C_; ++cc) a = fmaf(gsm[b2][cc], cw1[m * C_ + cc], a);
        hsm[b2][m] = fmaxf(a, 0.f);
    }
    __syncthreads();
    float v[9];
    float mean = 0.f;
#pragma unroll
    for (int t = 0; t < 9; ++t) {
        int o = c * 9 + t;
        float a = cb2[o];
#pragma unroll
        for (int m = 0; m < MID_; ++m) a = fmaf(hsm[b][m], cw2[o * MID_ + m], a);
        v[t] = a;
        mean += a;
    }
    mean *= (1.f / 9.f);
    float var = 0.f;
#pragma unroll
    for (int t = 0; t < 9; ++t) { float d = v[t] - mean; var += d * d; }
    float inv = 1.f / (sqrtf(var * (1.f / 8.f)) + 1e-10f);
#pragma unroll
    for (int t = 0; t < 9; ++t)
        cf[((size_t)b * C_ + c) * 9 + t] = (v[t] - mean) * inv * cstd[c * 9 + t];
}

// ---------- apply: patches * cf * s [-> relu -> s_next + gap partials | -> +resid] ----------
// PASS1: grid (2, 64, B);    computes out1=relu(ddf), fused s2 + gap2 partials
// PASS2: grid (2, 64, B*2);  channel-split halves, adds residual
template<bool PASS1>
__global__ __launch_bounds__(256) void apply_kernel(const float* __restrict__ in,
    const float* __restrict__ sarr, const float* __restrict__ cf,
    const float* __restrict__ swn, const float* __restrict__ sbn,
    const float* __restrict__ sstdn, const float* __restrict__ resid,
    float* __restrict__ out, float* __restrict__ snext, float* __restrict__ gpn) {
    const int tid = threadIdx.x;
    const int lane = tid & 63, wv = tid >> 6;
    const int col0 = (blockIdx.x * 64 + lane) * 2;
    const int row  = blockIdx.y * 4 + wv;
    int b, c0, cN;
    if (PASS1) { b = blockIdx.z; c0 = 0; cN = C_; }
    else       { b = blockIdx.z >> 1; c0 = (blockIdx.z & 1) * (C_ / 2); cN = C_ / 2; }
    __shared__ float lg[4][C_];

    // load s at the 2 pixels (9 taps)
    float s0[9], s1[9];
    {
        const float* sp = sarr + ((size_t)b * 9) * HW_ + (size_t)row * W_ + col0;
#pragma unroll
        for (int t = 0; t < 9; ++t) {
            float2 v = *(const float2*)(sp + (size_t)t * HW_);
            s0[t] = v.x; s1[t] = v.y;
        }
    }
    float nt0[9], nt1[9];
    if (PASS1) {
#pragma unroll
        for (int t = 0; t < 9; ++t) { float bb = sbn[t]; nt0[t] = bb; nt1[t] = bb; }
    }

    const bool rup = row > 0, rdn = row < H_ - 1;
    const bool cl = col0 > 0, cr = (col0 + 2) < W_;
    const size_t pix = (size_t)row * W_ + col0;
    const float* base = in + ((size_t)b * C_ + c0) * HW_ + pix;
    const float* cfb  = cf + ((size_t)b * C_ + c0) * 9;
    float* outp = out + ((size_t)b * C_ + c0) * HW_ + pix;
    const float* rbase = PASS1 ? nullptr : (resid + ((size_t)b * C_ + c0) * HW_ + pix);

    for (int c = 0; c < cN; ++c) {
        const float* p = base + (size_t)c * HW_;
        float m[3][4];   // rows -1..1 x cols col0-1..col0+2
#pragma unroll
        for (int dr = 0; dr < 3; ++dr) {
            const float* rp = p + (dr - 1) * W_;
            const bool rv = (dr == 0) ? rup : ((dr == 2) ? rdn : true);
            float2 mid = rv ? *(const float2*)rp : make_float2(0.f, 0.f);
            m[dr][1] = mid.x; m[dr][2] = mid.y;
            m[dr][0] = (rv && cl) ? rp[-1] : 0.f;
            m[dr][3] = (rv && cr) ? rp[2] : 0.f;
        }
        float acc0 = 0.f, acc1 = 0.f;
#pragma unroll
        for (int dr = 0; dr < 3; ++dr)
#pragma unroll
            for (int dc = 0; dc < 3; ++dc) {
                const int t = dr * 3 + dc;
                const float w = cfb[c * 9 + t];
                acc0 = fmaf(m[dr][dc]     * s0[t], w, acc0);
                acc1 = fmaf(m[dr][dc + 1] * s1[t], w, acc1);
            }
        float2 o;
        if (PASS1) {
            o.x = fmaxf(acc0, 0.f);
            o.y = fmaxf(acc1, 0.f);
#pragma unroll
            for (int t = 0; t < 9; ++t) {
                float wt = swn[t * C_ + c];
                nt0[t] = fmaf(o.x, wt, nt0[t]);
                nt1[t] = fmaf(o.y, wt, nt1[t]);
            }
            float gs = wave_reduce64(o.x + o.y);
            if (lane == 0) lg[wv][c] = gs;
        } else {
            float2 rv = *(const float2*)(rbase + (size_t)c * HW_);
            o.x = acc0 + rv.x;
            o.y = acc1 + rv.y;
        }
        *(float2*)(outp + (size_t)c * HW_) = o;
    }

    if (PASS1) {
        fnorm9(nt0, sstdn);
        fnorm9(nt1, sstdn);
        float* sp = snext + ((size_t)b * 9) * HW_ + pix;
#pragma unroll
        for (int t = 0; t < 9; ++t)
            *(float2*)(sp + (size_t)t * HW_) = make_float2(nt0[t], nt1[t]);
        __syncthreads();
        if (tid < C_) {
            float s4 = lg[0][tid] + lg[1][tid] + lg[2][tid] + lg[3][tid];
            gpn[((size_t)b * C_ + tid) * NPB_ + blockIdx.y * gridDim.x + blockIdx.x] = s4;
        }
    }
}

// ================= fallback (round-1 path, smaller ws need) =================
__global__ __launch_bounds__(256) void gap_kernel(const float* __restrict__ in,
                                                  float* __restrict__ g) {
    int bc = blockIdx.x;
    const float4* p4 = (const float4*)(in + (size_t)bc * HW_);
    float sum = 0.f;
    for (int i = threadIdx.x; i < HW_ / 4; i += 256) {
        float4 v = p4[i];
        sum += (v.x + v.y) + (v.z + v.w);
    }
    __shared__ float red[256];
    red[threadIdx.x] = sum;
    __syncthreads();
    for (int s = 128; s > 0; s >>= 1) {
        if (threadIdx.x < s) red[threadIdx.x] += red[threadIdx.x + s];
        __syncthreads();
    }
    if (threadIdx.x == 0) g[bc] = red[0] * (1.0f / HW_);
}

__global__ __launch_bounds__(256) void cf_kernel(const float* __restrict__ g,
    const float* __restrict__ cw1, const float* __restrict__ cb1,
    const float* __restrict__ cw2, const float* __restrict__ cb2,
    const float* __restrict__ cstd, float* __restrict__ cf) {
    __shared__ float hsm[B_][MID_];
    int tid = threadIdx.x;
    if (tid < B_ * MID_) {
        int b = tid / MID_, m = tid % MID_;
        float acc = cb1[m];
        for (int c = 0; c < C_; ++c) acc = fmaf(g[b * C_ + c], cw1[m * C_ + c], acc);
        hsm[b][m] = fmaxf(acc, 0.f);
    }
    __syncthreads();
    int b = tid >> 6, c = tid & 63;
    float v[9];
    float mean = 0.f;
#pragma unroll
    for (int t = 0; t < 9; ++t) {
        int o = c * 9 + t;
        float acc = cb2[o];
#pragma unroll
        for (int m = 0; m < MID_; ++m) acc = fmaf(hsm[b][m], cw2[o * MID_ + m], acc);
        v[t] = acc;
        mean += acc;
    }
    mean *= (1.f / 9.f);
    float var = 0.f;
#pragma unroll
    for (int t = 0; t < 9; ++t) { float d = v[t] - mean; var += d * d; }
    float inv = 1.f / (sqrtf(var * (1.f / 8.f)) + 1e-10f);
#pragma unroll
    for (int t = 0; t < 9; ++t)
        cf[(b * C_ + c) * 9 + t] = (v[t] - mean) * inv * cstd[c * 9 + t];
}

template <bool RELU, bool RESID>
__global__ __launch_bounds__(256) void ddf_main(const float* __restrict__ in,
    const float* __restrict__ sw, const float* __restrict__ sb,
    const float* __restrict__ sstd, const float* __restrict__ cf,
    const float* __restrict__ resid, float* __restrict__ out) {
    const int tx = threadIdx.x & 63, ty = threadIdx.x >> 6;
    const int w = blockIdx.x * 64 + tx;
    const int h = blockIdx.y * 4 + ty;
    const int b = blockIdx.z;
    const float* xb = in + (size_t)b * C_ * HW_;
    float s[9];
#pragma unroll
    for (int t = 0; t < 9; ++t) s[t] = sb[t];
    {
        const float* xp = xb + h * W_ + w;
        for (int c = 0; c < C_; ++c) {
            float xv = xp[(size_t)c * HW_];
#pragma unroll
            for (int t = 0; t < 9; ++t) s[t] = fmaf(xv, sw[t * C_ + c], s[t]);
        }
    }
    float mean = 0.f;
#pragma unroll
    for (int t = 0; t < 9; ++t) mean += s[t];
    mean *= (1.f / 9.f);
    float var = 0.f;
#pragma unroll
    for (int t = 0; t < 9; ++t) { float d = s[t] - mean; var += d * d; }
    float inv = 1.f / (sqrtf(var * (1.f / 8.f)) + 1e-10f);
#pragma unroll
    for (int t = 0; t < 9; ++t) s[t] = (s[t] - mean) * inv * sstd[t];
    const bool rok0 = (h > 0), rok2 = (h < H_ - 1);
    const bool cok0 = (w > 0), cok2 = (w < W_ - 1);
    const float* cfb = cf + b * (C_ * 9);
    const size_t base = (size_t)h * W_ + w;
    const size_t bbase = (size_t)b * C_ * HW_ + base;
    for (int c = 0; c < C_; ++c) {
        const float* xc = xb + (size_t)c * HW_ + base;
        float acc = 0.f;
#pragma unroll
        for (int i = 0; i < 3; ++i) {
            const bool rok = (i == 0) ? rok0 : ((i == 2) ? rok2 : true);
#pragma unroll
            for (int j = 0; j < 3; ++j) {
                const bool cok = (j == 0) ? cok0 : ((j == 2) ? cok2 : true);
                float xv = (rok && cok) ? xc[(i - 1) * W_ + (j - 1)] : 0.f;
                acc = fmaf(xv, cfb[c * 9 + i * 3 + j] * s[i * 3 + j], acc);
            }
        }
        if (RELU) acc = fmaxf(acc, 0.f);
        size_t oidx = bbase + (size_t)c * HW_;
        if (RESID) acc += resid[oidx];
        out[oidx] = acc;
    }
}

extern "C" void kernel_launch(void* const* d_in, const int* in_sizes, int n_in,
                              void* d_out, int out_size, void* d_ws, size_t ws_size,
                              hipStream_t stream) {
    const float* x     = (const float*)d_in[0];
    const float* sw1   = (const float*)d_in[1];
    const float* sb1   = (const float*)d_in[2];
    const float* sstd1 = (const float*)d_in[3];
    const float* cw1_1 = (const float*)d_in[4];
    const float* cb1_1 = (const float*)d_in[5];
    const float* cw2_1 = (const float*)d_in[6];
    const float* cb2_1 = (const float*)d_in[7];
    const float* cstd1 = (const float*)d_in[8];
    const float* sw2   = (const float*)d_in[9];
    const float* sb2   = (const float*)d_in[10];
    const float* sstd2 = (const float*)d_in[11];
    const float* cw1_2 = (const float*)d_in[12];
    const float* cb1_2 = (const float*)d_in[13];
    const float* cw2_2 = (const float*)d_in[14];
    const float* cb2_2 = (const float*)d_in[15];
    const float* cstd2 = (const float*)d_in[16];
    float* outp = (float*)d_out;

    const size_t n_out1 = (size_t)B_ * C_ * HW_;     // 16,777,216
    const size_t n_s    = (size_t)B_ * 9 * HW_;      // 2,359,296
    const size_t n_cf   = (size_t)B_ * C_ * 9;       // 2,304
    const size_t n_gp   = (size_t)B_ * C_ * NPB_;    // 32,768
    const size_t need_new = (n_out1 + 2 * n_s + 2 * n_cf + 2 * n_gp) * sizeof(float);

    if (ws_size >= need_new) {
        float* out1 = (float*)d_ws;
        float* s1   = out1 + n_out1;
        float* s2   = s1 + n_s;
        float* cf1  = s2 + n_s;
        float* cf2  = cf1 + n_cf;
        float* gp1  = cf2 + n_cf;
        float* gp2  = gp1 + n_gp;

        dim3 gmain(W_ / 128, H_ / 4, B_);
        dim3 gmain2(W_ / 128, H_ / 4, B_ * 2);

        prep_kernel<<<gmain, 256, 0, stream>>>(x, sw1, sb1, sstd1, s1, gp1);
        cfk<<<1, 256, 0, stream>>>(gp1, cw1_1, cb1_1, cw2_1, cb2_1, cstd1, cf1);
        apply_kernel<true><<<gmain, 256, 0, stream>>>(x, s1, cf1, sw2, sb2, sstd2,
                                                      nullptr, out1, s2, gp2);
        cfk<<<1, 256, 0, stream>>>(gp2, cw1_2, cb1_2, cw2_2, cb2_2, cstd2, cf2);
        apply_kernel<false><<<gmain2, 256, 0, stream>>>(out1, s2, cf2, nullptr, nullptr,
                                                        nullptr, x, outp, nullptr, nullptr);
        return;
    }

    // fallback (round-1 structure)
    const size_t need_old = (n_out1 + 256 + n_cf) * sizeof(float);
    if (ws_size < need_old) return;
    float* out1 = (float*)d_ws;
    float* g    = out1 + n_out1;
    float* cfb  = g + 256;
    dim3 grid(W_ / 64, H_ / 4, B_);
    gap_kernel<<<B_ * C_, 256, 0, stream>>>(x, g);
    cf_kernel<<<1, 256, 0, stream>>>(g, cw1_1, cb1_1, cw2_1, cb2_1, cstd1, cfb);
    ddf_main<true, false><<<grid, 256, 0, stream>>>(x, sw1, sb1, sstd1, cfb, nullptr, out1);
    gap_kernel<<<B_ * C_, 256, 0, stream>>>(out1, g);
    cf_kernel<<<1, 256, 0, stream>>>(g, cw1_2, cb1_2, cw2_2, cb2_2, cstd2, cfb);
    ddf_main<false, true><<<grid, 256, 0, stream>>>(out1, sw2, sb2, sstd2, cfb, x, outp);
}